// Round 6
// baseline (618.697 us; speedup 1.0000x reference)
//
#include <hip/hip_runtime.h>

#define NSTEPS 10
#define CSH    9            // 512 nodes per scan block
#define SPLIT  8            // threads per node in step kernel
#define EPK    655360.0f    // ep quantization scale (0.05 -> 32768)
#define EPI    (1.0f/655360.0f)

// ---------------- k_cnt: per-node degree histogram (+ init fold) ----------------
__global__ void k_cnt(const int* __restrict__ dst, unsigned* __restrict__ cnt,
                      const float* __restrict__ prior, float* __restrict__ p,
                      float* __restrict__ rp, unsigned* __restrict__ tick,
                      int E, int N) {
    int i = blockIdx.x * blockDim.x + threadIdx.x;
    if (i == 0) tick[0] = 0u;
    if (i < N) { float v = prior[i]; p[i] = v; rp[i] = 1.0f - v; }
    if (i < E) atomicAdd(&cnt[dst[i]], 1u);
}

// ---------------- k_scan: per-block padded inclusive scan of degrees ----------------
// 512 nodes/block; block totals scanned by the last-arriving block (ticket, as in
// the proven kS1 pattern). cnt[] is overwritten in place with the padded inclusive
// scan local to the block.
__global__ __launch_bounds__(512) void k_scan(unsigned* __restrict__ cnt,
                                              unsigned* __restrict__ bt,
                                              unsigned* __restrict__ base,
                                              unsigned* __restrict__ tick, int NC) {
    __shared__ unsigned wpart[8];
    __shared__ int lastf;
    int b = blockIdx.x, t = threadIdx.x;
    int lane = t & 63, wid = t >> 6;                  // 8 waves
    unsigned idx = ((unsigned)b << CSH) + (unsigned)t;
    unsigned c = cnt[idx];
    unsigned ps = (c + 3u) & ~3u;                     // pad rows to x4 (uint4)
    unsigned inc = ps;
    #pragma unroll
    for (int off = 1; off < 64; off <<= 1) {
        unsigned u = __shfl_up(inc, off, 64);
        if (lane >= off) inc += u;
    }
    if (lane == 63) wpart[wid] = inc;
    __syncthreads();
    if (wid == 0) {
        unsigned pv = (lane < 8) ? wpart[lane] : 0u;
        #pragma unroll
        for (int off = 1; off < 8; off <<= 1) {
            unsigned u = __shfl_up(pv, off, 64);
            if (lane >= off) pv += u;
        }
        if (lane < 8) wpart[lane] = pv;
    }
    __syncthreads();
    unsigned incl = inc + (wid ? wpart[wid - 1] : 0u);
    cnt[idx] = incl;                                  // padded inclusive, block-local
    if (t == 511) {
        __hip_atomic_store(&bt[b], incl, __ATOMIC_RELAXED, __HIP_MEMORY_SCOPE_AGENT);
        unsigned r = __hip_atomic_fetch_add(tick, 1u, __ATOMIC_ACQ_REL,
                                            __HIP_MEMORY_SCOPE_AGENT);
        lastf = (r == (unsigned)(NC - 1)) ? 1 : 0;
    }
    __syncthreads();
    if (!lastf) return;
    // exclusive scan of the NC block totals -> base[] (NC <= 256; waves 0..3)
    unsigned x = 0u, inc2 = 0u;
    if (t < 256) {
        x = (t < NC) ? __hip_atomic_load(&bt[t], __ATOMIC_RELAXED,
                                         __HIP_MEMORY_SCOPE_AGENT) : 0u;
        inc2 = x;
        #pragma unroll
        for (int off = 1; off < 64; off <<= 1) {
            unsigned u = __shfl_up(inc2, off, 64);
            if (lane >= off) inc2 += u;
        }
        if (lane == 63) wpart[wid] = inc2;
    }
    __syncthreads();
    if (wid == 0) {
        unsigned pv = (lane < 4) ? wpart[lane] : 0u;
        #pragma unroll
        for (int off = 1; off < 4; off <<= 1) {
            unsigned u = __shfl_up(pv, off, 64);
            if (lane >= off) pv += u;
        }
        if (lane < 4) wpart[lane] = pv;
    }
    __syncthreads();
    if (t < NC)
        __hip_atomic_store(&base[t], inc2 + (wid ? wpart[wid - 1] : 0u) - x,
                           __ATOMIC_RELAXED, __HIP_MEMORY_SCOPE_AGENT);
}

// ---------------- k_rows: row ranges + placement cursors ----------------
__global__ void k_rows(const unsigned* __restrict__ cnt, const unsigned* __restrict__ base,
                       uint2* __restrict__ rowse, unsigned* __restrict__ cur, int N) {
    int n = blockIdx.x * blockDim.x + threadIdx.x;
    if (n >= N) return;
    int b = n >> CSH, tl = n & ((1 << CSH) - 1);
    unsigned incl = cnt[n];
    unsigned prev = tl ? cnt[n - 1] : 0u;
    unsigned bs = base[b];
    rowse[n] = make_uint2(bs + prev, bs + incl);      // padded end; pads are zero words
    cur[n] = bs + prev;
}

// ---------------- k_place: one streamed pass; atomic bump per node ----------------
// Intra-row edge order is nondeterministic (atomic race) -- numerically irrelevant:
// absmax is dominated by the 15-bit weight quantization, not float add order.
__global__ void k_place(const int* __restrict__ src, const int* __restrict__ dst,
                        const float* __restrict__ ep, unsigned* __restrict__ cur,
                        unsigned* __restrict__ csr4, int E) {
    int i = blockIdx.x * blockDim.x + threadIdx.x;
    if (i >= E) return;
    unsigned wq = (unsigned)(ep[i] * EPK + 0.5f);
    if (wq > 32767u) wq = 32767u;
    unsigned pos = atomicAdd(&cur[dst[i]], 1u);
    csr4[pos] = (unsigned)src[i] | (wq << 17);
}

// ---------------- fused step: SPLIT threads/node, up-front dual uint4, shfl combine ----------------
__global__ __launch_bounds__(256) void k_step8(const unsigned* __restrict__ csr4,
                        const uint2* __restrict__ rowse,
                        const float* __restrict__ p_in, float* __restrict__ p_out,
                        float* __restrict__ rp, float* __restrict__ out, int N, int wout) {
    int g = blockIdx.x * blockDim.x + threadIdx.x;
    int node = g >> 3, q = g & 7;
    if (node >= N) return;
    uint2 se = rowse[node];
    unsigned j0 = se.x + (unsigned)q * 4u, e = se.y;
    uint4 a = make_uint4(0u, 0u, 0u, 0u);
    uint4 b = make_uint4(0u, 0u, 0u, 0u);
    if (j0 < e)        a = *(const uint4*)(csr4 + j0);
    if (j0 + 32u < e)  b = *(const uint4*)(csr4 + j0 + 32u);
    float d = 0.0f;
    d += (float)(a.x >> 17) * p_in[a.x & 0x1FFFFu];
    d += (float)(a.y >> 17) * p_in[a.y & 0x1FFFFu];
    d += (float)(a.z >> 17) * p_in[a.z & 0x1FFFFu];
    d += (float)(a.w >> 17) * p_in[a.w & 0x1FFFFu];
    d += (float)(b.x >> 17) * p_in[b.x & 0x1FFFFu];
    d += (float)(b.y >> 17) * p_in[b.y & 0x1FFFFu];
    d += (float)(b.z >> 17) * p_in[b.z & 0x1FFFFu];
    d += (float)(b.w >> 17) * p_in[b.w & 0x1FFFFu];
    if (j0 + 64u < e) {                  // ultra-rare (row > 64 edges)
        for (unsigned j = j0 + 64u; j < e; j += 32u) {
            uint4 qv = *(const uint4*)(csr4 + j);
            d += (float)(qv.x >> 17) * p_in[qv.x & 0x1FFFFu];
            d += (float)(qv.y >> 17) * p_in[qv.y & 0x1FFFFu];
            d += (float)(qv.z >> 17) * p_in[qv.z & 0x1FFFFu];
            d += (float)(qv.w >> 17) * p_in[qv.w & 0x1FFFFu];
        }
    }
    d += __shfl_xor(d, 1);
    d += __shfl_xor(d, 2);
    d += __shfl_xor(d, 4);
    if (q == 0) {
        d *= EPI;
        float r0 = rp[node];
        float pt = r0 * (1.0f - __expf(-d));
        float rn = r0 * (1.0f - pt);
        if (wout) {
            out[node] = 1.0f - rn;       // p_out/rp dead after last step
        } else {
            p_out[node] = pt;
            rp[node]    = rn;
        }
    }
}

// ---------------- fallback (global-atomic path, ~1.2 MB ws) ----------------
__global__ void fb_init(const float* __restrict__ prior, float* __restrict__ p,
                        float* __restrict__ rp, float* __restrict__ delta, int n) {
    int i = blockIdx.x * blockDim.x + threadIdx.x;
    if (i < n) { float v = prior[i]; p[i] = v; rp[i] = 1.0f - v; delta[i] = 0.0f; }
}
__global__ void fb_edges(const int* __restrict__ src, const int* __restrict__ dst,
                         const float* __restrict__ ep, const float* __restrict__ p,
                         float* __restrict__ delta, int E) {
    int i = blockIdx.x * blockDim.x + threadIdx.x;
    if (i < E) atomicAdd(&delta[dst[i]], ep[i] * p[src[i]]);
}
__global__ void fb_nodes(float* __restrict__ p, float* __restrict__ rp,
                         float* __restrict__ delta, float* __restrict__ out, int n) {
    int i = blockIdx.x * blockDim.x + threadIdx.x;
    if (i < n) {
        float d = delta[i]; delta[i] = 0.0f;
        float r0 = rp[i];
        float pt = r0 * (1.0f - __expf(-d));
        float rn = r0 * (1.0f - pt);
        p[i] = pt; rp[i] = rn; out[i] = 1.0f - rn;
    }
}

extern "C" void kernel_launch(void* const* d_in, const int* in_sizes, int n_in,
                              void* d_out, int out_size, void* d_ws, size_t ws_size,
                              hipStream_t stream) {
    const float* prior = (const float*)d_in[0];
    const int*   eidx  = (const int*)d_in[1];   // [2, E] int32 (jax x64 disabled)
    const float* ep    = (const float*)d_in[2];
    float* out = (float*)d_out;

    const int N = in_sizes[0];
    const int E = in_sizes[2];
    const int* src = eidx;
    const int* dst = eidx + E;

    const int NC  = (N + (1 << CSH) - 1) >> CSH;      // scan blocks (512 nodes each)
    const int NCW = NC << CSH;                        // cnt entries (rounded up)

    // carve workspace (cnt and csr4 adjacent -> single memset zeroes both)
    char* w = (char*)d_ws;
    auto carve = [&](size_t bytes) -> void* {
        void* r = (void*)w;
        w += (bytes + 255) & ~(size_t)255;
        return r;
    };
    float*    p0    = (float*)carve((size_t)N * 4);
    float*    p1    = (float*)carve((size_t)N * 4);
    float*    rp    = (float*)carve((size_t)N * 4);
    uint2*    rowse = (uint2*)carve((size_t)N * 8);
    unsigned* cur   = (unsigned*)carve((size_t)N * 4);
    unsigned* bt    = (unsigned*)carve(256 * 4);
    unsigned* base  = (unsigned*)carve(256 * 4);
    unsigned* tick  = (unsigned*)carve(256);
    unsigned* cnt   = (unsigned*)carve((size_t)NCW * 4);
    size_t csr4_words = (size_t)E + 4 * (size_t)N + 256;
    unsigned* csr4  = (unsigned*)carve(csr4_words * 4);
    size_t need = (size_t)(w - (char*)d_ws);
    size_t zspan = (size_t)((char*)csr4 - (char*)cnt) + csr4_words * 4;

    bool ok = (need <= ws_size) && (NC <= 256) && (N < (1 << 17));

    if (ok) {
        const int BT = 256;
        hipMemsetAsync(cnt, 0, zspan, stream);        // zeroes cnt + csr4 (pads stay 0)
        int gmax = (E > N ? E : N);
        k_cnt<<<(gmax + BT - 1) / BT, BT, 0, stream>>>(dst, cnt, prior, p0, rp,
                                                       tick, E, N);
        k_scan<<<NC, 512, 0, stream>>>(cnt, bt, base, tick, NC);
        k_rows<<<(N + BT - 1) / BT, BT, 0, stream>>>(cnt, base, rowse, cur, N);
        k_place<<<(E + BT - 1) / BT, BT, 0, stream>>>(src, dst, ep, cur, csr4, E);
        float* pin = p0; float* pout = p1;
        const int nb_step = (N * SPLIT + BT - 1) / BT;
        for (int t = 0; t < NSTEPS; ++t) {
            k_step8<<<nb_step, BT, 0, stream>>>(csr4, rowse, pin, pout,
                                                rp, out, N, (t == NSTEPS - 1) ? 1 : 0);
            float* tmp = pin; pin = pout; pout = tmp;
        }
    } else {
        float* delta = (float*)d_ws;
        float* p     = delta + N;
        float* rpf   = p + N;
        const int BT = 256;
        fb_init<<<(N + BT - 1) / BT, BT, 0, stream>>>(prior, p, rpf, delta, N);
        for (int t = 0; t < NSTEPS; ++t) {
            fb_edges<<<(E + BT - 1) / BT, BT, 0, stream>>>(src, dst, ep, p, delta, E);
            fb_nodes<<<(N + BT - 1) / BT, BT, 0, stream>>>(p, rpf, delta, out, N);
        }
    }
}

// Round 7
// 282.836 us; speedup vs baseline: 2.1875x; 2.1875x over previous
//
#include <hip/hip_runtime.h>

#define NSTEPS 10
#define CSHIFT 9            // 512 nodes per coarse bucket
#define CNODES 512
#define PBLK   1024         // partition blocks for hist/scatter
#define SCHUNK 3328         // max edges per scatter chunk (LDS staging)
#define SSLOT  16           // register slots per scatter thread (16*256 >= chunk)
#define LCAP   17920        // k_group LDS stage capacity (entries; 143.4 KB of 160)
#define GAP    2048         // per-bucket slack in csr4 (512 nodes x <4 pad)
#define SPLIT  8            // threads per node in step kernel
#define EPK    655360.0f    // ep quantization scale (0.05 -> 32768)
#define EPI    (1.0f/655360.0f)

// ---------------- pass A: histogram of coarse buckets (+ init fold) ----------------
// histT layout TRANSPOSED: histT[bin*PBLK + blk] so kS1 reads/writes coalesced rows.
__global__ void k_hist(const int* __restrict__ dst, unsigned* __restrict__ histT,
                       const float* __restrict__ prior, float* __restrict__ p,
                       float* __restrict__ rp, unsigned* __restrict__ tick,
                       int E, int NC, int chunk, int N) {
    extern __shared__ unsigned h[];
    int gid = blockIdx.x * blockDim.x + threadIdx.x;
    if (gid == 0) tick[0] = 0u;                       // ticket for fused kS1/kS2
    if (gid < N) { float v = prior[gid]; p[gid] = v; rp[gid] = 1.0f - v; }
    for (int i = threadIdx.x; i < NC; i += blockDim.x) h[i] = 0u;
    __syncthreads();
    int s = blockIdx.x * chunk, e = min(s + chunk, E);
    for (int i = s + threadIdx.x; i < e; i += blockDim.x)
        atomicAdd(&h[((unsigned)dst[i]) >> CSHIFT], 1u);
    __syncthreads();
    for (int i = threadIdx.x; i < NC; i += blockDim.x)
        histT[(size_t)i * PBLK + blockIdx.x] = h[i];
}

// ---- kS1 (fused with kS2): per-bin scan over PBLK blocks; last block scans totals ----
// transposed histT -> fully coalesced row access; shfl-based scans.
__global__ __launch_bounds__(PBLK) void kS1(unsigned* __restrict__ histT,
                                            unsigned* __restrict__ binTot,
                                            unsigned* __restrict__ cbp,
                                            unsigned* __restrict__ tick, int NC) {
    __shared__ unsigned wsum[16];
    __shared__ int lastf;
    int bin = blockIdx.x, t = threadIdx.x;
    int lane = t & 63, wid = t >> 6;                  // 16 waves
    unsigned* row = histT + (size_t)bin * PBLK;
    unsigned v = row[t];
    unsigned inc = v;
    #pragma unroll
    for (int off = 1; off < 64; off <<= 1) {
        unsigned u = __shfl_up(inc, off, 64);
        if (lane >= off) inc += u;
    }
    if (lane == 63) wsum[wid] = inc;
    __syncthreads();
    if (wid == 0) {
        unsigned pv = (lane < 16) ? wsum[lane] : 0u;
        #pragma unroll
        for (int off = 1; off < 16; off <<= 1) {
            unsigned u = __shfl_up(pv, off, 64);
            if (lane >= off) pv += u;
        }
        if (lane < 16) wsum[lane] = pv;
    }
    __syncthreads();
    unsigned incl = inc + (wid ? wsum[wid - 1] : 0u);
    row[t] = incl - v;                                // exclusive within bin
    if (t == PBLK - 1) {
        __hip_atomic_store(&binTot[bin], incl, __ATOMIC_RELAXED,
                           __HIP_MEMORY_SCOPE_AGENT);
        unsigned r = __hip_atomic_fetch_add(tick, 1u, __ATOMIC_ACQ_REL,
                                            __HIP_MEMORY_SCOPE_AGENT);
        lastf = (r == (unsigned)(NC - 1)) ? 1 : 0;
    }
    __syncthreads();
    if (!lastf) return;
    // ---- kS2 body: exclusive scan of x4-padded bucket totals -> cbp (waves 0..3) ----
    unsigned x = 0u, inc2 = 0u;
    if (t < 256) {
        unsigned bt = (t < NC) ? __hip_atomic_load(&binTot[t], __ATOMIC_RELAXED,
                                                   __HIP_MEMORY_SCOPE_AGENT) : 0u;
        x = (t < NC) ? ((bt + 3u) & ~3u) : 0u;
        inc2 = x;
        #pragma unroll
        for (int off = 1; off < 64; off <<= 1) {
            unsigned u = __shfl_up(inc2, off, 64);
            if (lane >= off) inc2 += u;
        }
        if (lane == 63) wsum[wid] = inc2;
    }
    __syncthreads();
    if (wid == 0) {
        unsigned pv = (lane < 4) ? wsum[lane] : 0u;
        #pragma unroll
        for (int off = 1; off < 4; off <<= 1) {
            unsigned u = __shfl_up(pv, off, 64);
            if (lane >= off) pv += u;
        }
        if (lane < 4) wsum[lane] = pv;
    }
    __syncthreads();
    if (t < 256) {
        unsigned incl2 = inc2 + (wid ? wsum[wid - 1] : 0u);
        if (t < NC) cbp[t] = incl2 - x;
        if (t == NC - 1) cbp[NC] = incl2;
    }
}

// ---------------- scatter: register-staged LDS counting-sort, coalesced run writes ----------------
__global__ __launch_bounds__(256) void k_scatter(const int* __restrict__ src,
                          const int* __restrict__ dst, const float* __restrict__ ep,
                          const unsigned* __restrict__ histT, const unsigned* __restrict__ cbp,
                          uint2* __restrict__ mid, int E, int NC, int chunk) {
    __shared__ uint2 sbuf[SCHUNK];
    __shared__ unsigned cnt[256], sc[256], cur[256], gbase[256], wpart[4];
    int blk = blockIdx.x, tid = threadIdx.x;
    int lane = tid & 63, wid = tid >> 6;              // 4 waves
    cnt[tid] = 0u;
    if (tid < NC) gbase[tid] = histT[(size_t)tid * PBLK + blk] + cbp[tid];
    __syncthreads();
    int s = blk * chunk, e = min(s + chunk, E);
    unsigned av[SSLOT], yv[SSLOT];
    // pass 1: read + stage in registers, count bins
    #pragma unroll
    for (int k = 0; k < SSLOT; ++k) {
        int i = s + tid + k * 256;
        if (i < e) {
            unsigned d = (unsigned)dst[i];
            unsigned bin = d >> CSHIFT;
            unsigned wq = (unsigned)(ep[i] * EPK + 0.5f);
            if (wq > 32767u) wq = 32767u;
            av[k] = (unsigned)src[i] | (wq << 17);
            yv[k] = (d & 511u) | (bin << 9);
            atomicAdd(&cnt[bin], 1u);
        }
    }
    __syncthreads();
    // exclusive scan of 256 bins (shfl-based)
    unsigned x = cnt[tid];
    unsigned inc = x;
    #pragma unroll
    for (int off = 1; off < 64; off <<= 1) {
        unsigned u = __shfl_up(inc, off, 64);
        if (lane >= off) inc += u;
    }
    if (lane == 63) wpart[wid] = inc;
    __syncthreads();
    if (wid == 0) {
        unsigned pv = (lane < 4) ? wpart[lane] : 0u;
        #pragma unroll
        for (int off = 1; off < 4; off <<= 1) {
            unsigned u = __shfl_up(pv, off, 64);
            if (lane >= off) pv += u;
        }
        if (lane < 4) wpart[lane] = pv;
    }
    __syncthreads();
    unsigned excl = inc + (wid ? wpart[wid - 1] : 0u) - x;
    sc[tid] = excl; cur[tid] = excl;
    __syncthreads();
    // pass 2: permute into LDS from registers
    #pragma unroll
    for (int k = 0; k < SSLOT; ++k) {
        int i = s + tid + k * 256;
        if (i < e) {
            unsigned bin = yv[k] >> 9;
            unsigned pos = atomicAdd(&cur[bin], 1u);
            sbuf[pos] = make_uint2(av[k], yv[k]);
        }
    }
    __syncthreads();
    // pass 3: linear write-out; consecutive i in a bin -> consecutive global pos
    int cT = e - s;
    for (int i = tid; i < cT; i += 256) {
        uint2 r = sbuf[i];
        unsigned bin = r.y >> 9;
        mid[gbase[bin] + ((unsigned)i - sc[bin])] = make_uint2(r.x, r.y & 511u);
    }
}

// ---------------- group: one block per bucket; node-sort to x4-padded csr4 ----------------
// LDS-staged (no spill). Phase 1 batch-prefetches 8 loads/iter to collapse the
// dependent-latency chain (round-5 counters: 45us, VALUBusy 6% -> latency-bound).
// + step-0 fold with k_step8's exact dual-uint4 summation order.
__global__ __launch_bounds__(1024) void k_group(const uint2* __restrict__ mid,
                        const unsigned* __restrict__ binTot, const unsigned* __restrict__ cbp,
                        unsigned* __restrict__ csr4, uint2* __restrict__ rowse,
                        const float* __restrict__ p0, float* __restrict__ p1,
                        float* __restrict__ rp, int N, int NC) {
    __shared__ uint2 sm[LCAP];                        // 143.4 KB edge stage
    __shared__ unsigned cnt[CNODES], ts[CNODES], cur[CNODES], wpart[8];
    int nc = blockIdx.x, t = threadIdx.x;
    int lane = t & 63, wid = t >> 6;                  // 16 waves
    unsigned bm = cbp[nc];
    unsigned b4 = bm + (unsigned)nc * GAP;
    unsigned c  = binTot[nc];
    if (c > (unsigned)LCAP) c = (unsigned)LCAP;
    if (t < CNODES) cnt[t] = 0u;
    __syncthreads();
    // phase 1: stream mid -> LDS with 8-wide load batching, histogram nodes
    for (unsigned basei = 0; basei < c; basei += 8192u) {
        unsigned i0 = basei + (unsigned)t;
        uint2 v0 = (i0          < c) ? mid[bm + i0         ] : make_uint2(0u, 0u);
        uint2 v1 = (i0 + 1024u  < c) ? mid[bm + i0 + 1024u ] : make_uint2(0u, 0u);
        uint2 v2 = (i0 + 2048u  < c) ? mid[bm + i0 + 2048u ] : make_uint2(0u, 0u);
        uint2 v3 = (i0 + 3072u  < c) ? mid[bm + i0 + 3072u ] : make_uint2(0u, 0u);
        uint2 v4 = (i0 + 4096u  < c) ? mid[bm + i0 + 4096u ] : make_uint2(0u, 0u);
        uint2 v5 = (i0 + 5120u  < c) ? mid[bm + i0 + 5120u ] : make_uint2(0u, 0u);
        uint2 v6 = (i0 + 6144u  < c) ? mid[bm + i0 + 6144u ] : make_uint2(0u, 0u);
        uint2 v7 = (i0 + 7168u  < c) ? mid[bm + i0 + 7168u ] : make_uint2(0u, 0u);
        if (i0          < c) { sm[i0         ] = v0; atomicAdd(&cnt[v0.y], 1u); }
        if (i0 + 1024u  < c) { sm[i0 + 1024u ] = v1; atomicAdd(&cnt[v1.y], 1u); }
        if (i0 + 2048u  < c) { sm[i0 + 2048u ] = v2; atomicAdd(&cnt[v2.y], 1u); }
        if (i0 + 3072u  < c) { sm[i0 + 3072u ] = v3; atomicAdd(&cnt[v3.y], 1u); }
        if (i0 + 4096u  < c) { sm[i0 + 4096u ] = v4; atomicAdd(&cnt[v4.y], 1u); }
        if (i0 + 5120u  < c) { sm[i0 + 5120u ] = v5; atomicAdd(&cnt[v5.y], 1u); }
        if (i0 + 6144u  < c) { sm[i0 + 6144u ] = v6; atomicAdd(&cnt[v6.y], 1u); }
        if (i0 + 7168u  < c) { sm[i0 + 7168u ] = v7; atomicAdd(&cnt[v7.y], 1u); }
    }
    __syncthreads();
    unsigned ccnt = (t < CNODES) ? cnt[t] : 0u;
    unsigned ps = (ccnt + 3u) & ~3u;        // pad rows to x4 (uint4)
    unsigned inc = (t < CNODES) ? ps : 0u;
    #pragma unroll
    for (int off = 1; off < 64; off <<= 1) {
        unsigned u = __shfl_up(inc, off, 64);
        if (lane >= off) inc += u;
    }
    if (lane == 63 && wid < 8) wpart[wid] = inc;
    __syncthreads();
    if (wid == 0) {
        unsigned pv = (lane < 8) ? wpart[lane] : 0u;
        #pragma unroll
        for (int off = 1; off < 8; off <<= 1) {
            unsigned u = __shfl_up(pv, off, 64);
            if (lane >= off) pv += u;
        }
        if (lane < 8) wpart[lane] = pv;
    }
    __syncthreads();
    if (t < CNODES) {
        unsigned incl = inc + (wid ? wpart[wid - 1] : 0u);
        ts[t] = incl;                        // inclusive padded scan (kept for step-0)
        unsigned excl = incl - ps;
        cur[t] = excl;
        int node = (nc << CSHIFT) + t;
        if (node < N) rowse[node] = make_uint2(b4 + excl, b4 + excl + ps);
        for (unsigned i = ccnt; i < ps; ++i) csr4[b4 + excl + i] = 0u;  // zero only pads
    }
    __syncthreads();
    // phase 2: permute LDS stage -> csr4 (LDS reads are cheap; writes fire-and-forget)
    for (unsigned i = (unsigned)t; i < c; i += 1024u) {
        uint2 m = sm[i];
        unsigned pos = atomicAdd(&cur[m.y], 1u);
        csr4[b4 + pos] = m.x;
    }
    // ---- step-0 fold: 4 passes x 128 nodes x 8 q-threads; order == k_step8 ----
    __syncthreads();                         // csr4 writes visible block-wide
    #pragma unroll 1
    for (int pass = 0; pass < 4; ++pass) {
        int nl = pass * 128 + (t >> 3);
        int q  = t & 7;
        int node = (nc << CSHIFT) + nl;
        unsigned sL = nl ? ts[nl - 1] : 0u;
        unsigned eL = ts[nl];
        unsigned j0 = sL + (unsigned)q * 4u;
        uint4 a = make_uint4(0u, 0u, 0u, 0u);
        uint4 b = make_uint4(0u, 0u, 0u, 0u);
        if (node < N) {
            if (j0 < eL)        a = *(const uint4*)(csr4 + b4 + j0);
            if (j0 + 32u < eL)  b = *(const uint4*)(csr4 + b4 + j0 + 32u);
        }
        float d = 0.0f;
        d += (float)(a.x >> 17) * p0[a.x & 0x1FFFFu];
        d += (float)(a.y >> 17) * p0[a.y & 0x1FFFFu];
        d += (float)(a.z >> 17) * p0[a.z & 0x1FFFFu];
        d += (float)(a.w >> 17) * p0[a.w & 0x1FFFFu];
        d += (float)(b.x >> 17) * p0[b.x & 0x1FFFFu];
        d += (float)(b.y >> 17) * p0[b.y & 0x1FFFFu];
        d += (float)(b.z >> 17) * p0[b.z & 0x1FFFFu];
        d += (float)(b.w >> 17) * p0[b.w & 0x1FFFFu];
        if (node < N && j0 + 64u < eL) {     // ultra-rare (row > 64 edges)
            for (unsigned j = j0 + 64u; j < eL; j += 32u) {
                uint4 qv = *(const uint4*)(csr4 + b4 + j);
                d += (float)(qv.x >> 17) * p0[qv.x & 0x1FFFFu];
                d += (float)(qv.y >> 17) * p0[qv.y & 0x1FFFFu];
                d += (float)(qv.z >> 17) * p0[qv.z & 0x1FFFFu];
                d += (float)(qv.w >> 17) * p0[qv.w & 0x1FFFFu];
            }
        }
        d += __shfl_xor(d, 1);
        d += __shfl_xor(d, 2);
        d += __shfl_xor(d, 4);
        if (q == 0 && node < N) {
            d *= EPI;
            float r0 = rp[node];
            float pt = r0 * (1.0f - __expf(-d));
            float rn = r0 * (1.0f - pt);
            p1[node] = pt;
            rp[node] = rn;
        }
    }
}

// ---------------- fused step: SPLIT threads/node, up-front dual uint4, shfl combine ----------------
__global__ __launch_bounds__(256) void k_step8(const unsigned* __restrict__ csr4,
                        const uint2* __restrict__ rowse,
                        const float* __restrict__ p_in, float* __restrict__ p_out,
                        float* __restrict__ rp, float* __restrict__ out, int N, int wout) {
    int g = blockIdx.x * blockDim.x + threadIdx.x;
    int node = g >> 3, q = g & 7;
    if (node >= N) return;
    uint2 se = rowse[node];
    unsigned j0 = se.x + (unsigned)q * 4u, e = se.y;
    uint4 a = make_uint4(0u, 0u, 0u, 0u);
    uint4 b = make_uint4(0u, 0u, 0u, 0u);
    if (j0 < e)        a = *(const uint4*)(csr4 + j0);
    if (j0 + 32u < e)  b = *(const uint4*)(csr4 + j0 + 32u);
    float d = 0.0f;
    d += (float)(a.x >> 17) * p_in[a.x & 0x1FFFFu];
    d += (float)(a.y >> 17) * p_in[a.y & 0x1FFFFu];
    d += (float)(a.z >> 17) * p_in[a.z & 0x1FFFFu];
    d += (float)(a.w >> 17) * p_in[a.w & 0x1FFFFu];
    d += (float)(b.x >> 17) * p_in[b.x & 0x1FFFFu];
    d += (float)(b.y >> 17) * p_in[b.y & 0x1FFFFu];
    d += (float)(b.z >> 17) * p_in[b.z & 0x1FFFFu];
    d += (float)(b.w >> 17) * p_in[b.w & 0x1FFFFu];
    if (j0 + 64u < e) {                  // ultra-rare (row > 64 edges)
        for (unsigned j = j0 + 64u; j < e; j += 32u) {
            uint4 qv = *(const uint4*)(csr4 + j);
            d += (float)(qv.x >> 17) * p_in[qv.x & 0x1FFFFu];
            d += (float)(qv.y >> 17) * p_in[qv.y & 0x1FFFFu];
            d += (float)(qv.z >> 17) * p_in[qv.z & 0x1FFFFu];
            d += (float)(qv.w >> 17) * p_in[qv.w & 0x1FFFFu];
        }
    }
    d += __shfl_xor(d, 1);
    d += __shfl_xor(d, 2);
    d += __shfl_xor(d, 4);
    if (q == 0) {
        d *= EPI;
        float r0 = rp[node];
        float pt = r0 * (1.0f - __expf(-d));
        float rn = r0 * (1.0f - pt);
        if (wout) {
            out[node] = 1.0f - rn;       // p_out/rp dead after last step
        } else {
            p_out[node] = pt;
            rp[node]    = rn;
        }
    }
}

// ---------------- fallback (global-atomic path, ~1.2 MB ws) ----------------
__global__ void fb_init(const float* __restrict__ prior, float* __restrict__ p,
                        float* __restrict__ rp, float* __restrict__ delta, int n) {
    int i = blockIdx.x * blockDim.x + threadIdx.x;
    if (i < n) { float v = prior[i]; p[i] = v; rp[i] = 1.0f - v; delta[i] = 0.0f; }
}
__global__ void fb_edges(const int* __restrict__ src, const int* __restrict__ dst,
                         const float* __restrict__ ep, const float* __restrict__ p,
                         float* __restrict__ delta, int E) {
    int i = blockIdx.x * blockDim.x + threadIdx.x;
    if (i < E) atomicAdd(&delta[dst[i]], ep[i] * p[src[i]]);
}
__global__ void fb_nodes(float* __restrict__ p, float* __restrict__ rp,
                         float* __restrict__ delta, float* __restrict__ out, int n) {
    int i = blockIdx.x * blockDim.x + threadIdx.x;
    if (i < n) {
        float d = delta[i]; delta[i] = 0.0f;
        float r0 = rp[i];
        float pt = r0 * (1.0f - __expf(-d));
        float rn = r0 * (1.0f - pt);
        p[i] = pt; rp[i] = rn; out[i] = 1.0f - rn;
    }
}

extern "C" void kernel_launch(void* const* d_in, const int* in_sizes, int n_in,
                              void* d_out, int out_size, void* d_ws, size_t ws_size,
                              hipStream_t stream) {
    const float* prior = (const float*)d_in[0];
    const int*   eidx  = (const int*)d_in[1];   // [2, E] int32 (jax x64 disabled)
    const float* ep    = (const float*)d_in[2];
    float* out = (float*)d_out;

    const int N = in_sizes[0];
    const int E = in_sizes[2];
    const int* src = eidx;
    const int* dst = eidx + E;

    const int NC    = (N + CNODES - 1) >> CSHIFT;     // coarse buckets
    const int chunk = (E + PBLK - 1) / PBLK;

    // carve workspace
    char* w = (char*)d_ws;
    auto carve = [&](size_t bytes) -> void* {
        void* r = (void*)w;
        w += (bytes + 255) & ~(size_t)255;
        return r;
    };
    float*    p0     = (float*)carve((size_t)N * 4);
    float*    p1     = (float*)carve((size_t)N * 4);
    float*    rp     = (float*)carve((size_t)N * 4);
    uint2*    rowse  = (uint2*)carve((size_t)N * 8);
    unsigned* histT  = (unsigned*)carve((size_t)PBLK * 256 * 4);
    unsigned* binTot = (unsigned*)carve((size_t)NC * 4);
    unsigned* cbp    = (unsigned*)carve((size_t)(NC + 1) * 4);
    unsigned* tick   = (unsigned*)carve(256);
    uint2*    mid    = (uint2*)carve(((size_t)E + 4 * NC) * 8);
    unsigned* csr4   = (unsigned*)carve(((size_t)E + 4 * NC + (size_t)N * 4 +
                                         (size_t)NC * GAP + 64) * 4);
    size_t need = (size_t)(w - (char*)d_ws);

    // avg bucket = E*CNODES/N; LCAP must cover max bucket (Poisson, +>8 sigma margin)
    bool ok = (need <= ws_size) && (NC <= 256) && (chunk <= SCHUNK) &&
              (chunk <= SSLOT * 256) && (N < (1 << 17)) &&
              ((size_t)E * CNODES / (size_t)N + 1024 <= (size_t)LCAP);

    if (ok) {
        const int BT = 256;
        k_hist<<<PBLK, BT, NC * 4, stream>>>(dst, histT, prior, p0, rp, tick,
                                             E, NC, chunk, N);
        kS1<<<NC, PBLK, 0, stream>>>(histT, binTot, cbp, tick, NC);
        k_scatter<<<PBLK, BT, 0, stream>>>(src, dst, ep, histT, cbp, mid, E, NC, chunk);
        k_group<<<NC, 1024, 0, stream>>>(mid, binTot, cbp, csr4, rowse,
                                         p0, p1, rp, N, NC);   // does step 0 too
        float* pin = p1; float* pout = p0;
        const int nb_step = (N * SPLIT + BT - 1) / BT;
        for (int t = 1; t < NSTEPS; ++t) {
            k_step8<<<nb_step, BT, 0, stream>>>(csr4, rowse, pin, pout,
                                                rp, out, N, (t == NSTEPS - 1) ? 1 : 0);
            float* tmp = pin; pin = pout; pout = tmp;
        }
    } else {
        float* delta = (float*)d_ws;
        float* p     = delta + N;
        float* rpf   = p + N;
        const int BT = 256;
        fb_init<<<(N + BT - 1) / BT, BT, 0, stream>>>(prior, p, rpf, delta, N);
        for (int t = 0; t < NSTEPS; ++t) {
            fb_edges<<<(E + BT - 1) / BT, BT, 0, stream>>>(src, dst, ep, p, delta, E);
            fb_nodes<<<(N + BT - 1) / BT, BT, 0, stream>>>(p, rpf, delta, out, N);
        }
    }
}